// Round 1
// 275.800 us; speedup vs baseline: 1.0478x; 1.0478x over previous
//
#include <hip/hip_runtime.h>
#include <hip/hip_bf16.h>

typedef unsigned long long u64;
typedef unsigned int u32;

#define BATCH 16
#define NANCH 25200
#define NCLS 80
#define NFEAT 85
#define TOPK 1024
#define MAXDET 300
#define CONF_T 0.25f
#define IOU_T 0.45f
#define MAX_WH 7680.0f

#define TILE_A 64   // anchors per block (score kernel)

// async 16B global->LDS (gfx950). LDS dest is wave-uniform base + lane*16.
__device__ __forceinline__ void gload_lds16(const void* g, void* l) {
    __builtin_amdgcn_global_load_lds(
        (const __attribute__((address_space(1))) unsigned int*)g,
        (__attribute__((address_space(3))) unsigned int*)l, 16, 0, 0);
}

// ---------------------------------------------------------------------------
// Kernel 1: per-anchor score + 64-bit sort key.
// key = (ordered_score_bits << 32) | ((idx ^ 0xFFFF) << 8) | class
// One 64-anchor tile per 256-thr block; staging via async global_load_lds
// (width 16): each wave issues 6 outstanding 1 KiB chunks -> MLP-rich.
// At the 137 MB HBM read floor (~22 us) -- unchanged this round.
// ---------------------------------------------------------------------------
__global__ __launch_bounds__(256) void score_kernel(const float* __restrict__ in,
                                                    u64* __restrict__ keys) {
    __shared__ float ld[TILE_A * NFEAT];  // 21760 B
    const int b = blockIdx.y, tid = threadIdx.x;
    const int wv = tid >> 6, lane = tid & 63;
    const int a0 = blockIdx.x * TILE_A;
    const int na = min(TILE_A, NANCH - a0);          // 64 or 48
    const int nbytes = na * NFEAT * 4;               // 21760 or 16320
    const char* gbase = (const char*)(in + ((size_t)b * NANCH + a0) * NFEAT);
#pragma unroll
    for (int r = 0; r < 6; ++r) {
        const int off = (r * 4 + wv) << 10;
        const int myb = off + lane * 16;
        if (myb < nbytes)
            gload_lds16(gbase + myb, (char*)ld + off);
    }
    __syncthreads();   // drains vmcnt (global_load_lds tracked by vmcnt)
    const int a = tid >> 2, q = tid & 3;
    if (a < na) {
        const float* p = ld + a * NFEAT;
        float obj = p[4];
        float best = -1e30f;
        int bj = 0;
#pragma unroll
        for (int k = 0; k < 20; ++k) {
            float v = p[5 + q * 20 + k] * obj;
            if (v > best) { best = v; bj = q * 20 + k; }   // first-occurrence argmax
        }
#pragma unroll
        for (int d = 1; d < 4; d <<= 1) {
            float ob = __shfl_xor(best, d, 64);
            int oj = __shfl_xor(bj, d, 64);
            if (ob > best || (ob == best && oj < bj)) { best = ob; bj = oj; }
        }
        if (q == 0) {
            bool valid = (obj > CONF_T) && (best > CONF_T);
            float sc = valid ? best : -1.0f;
            u32 sb = __float_as_uint(sc);
            u32 ord = sb ^ ((sb & 0x80000000u) ? 0xFFFFFFFFu : 0x80000000u);
            int idx = a0 + a;
            keys[(size_t)b * NANCH + idx] =
                ((u64)ord << 32) | ((u64)((u32)(idx ^ 0xFFFF) & 0xFFFFu) << 8) | (u64)bj;
        }
    }
}

// ---------------------------------------------------------------------------
// Kernel 2: exact top-1024 per batch. Single-pass 12-bit radix select
// (4096-bin LDS histogram + hierarchical suffix scan) + >/== compaction +
// hybrid bitonic sort (jj<=64 in registers, jj>=128 in LDS).
// Pass A/B kept split: on buf overflow only ==-class keys are dropped,
// preserving exact top-k (fused >= pass could drop >-class keys).
// Block 0 also zero-inits out[0..1] (consumed by nms_finalize atomics,
// which runs stream-after -> ordering guaranteed; saves a memset dispatch).
// ---------------------------------------------------------------------------
__global__ __launch_bounds__(1024) void select_topk(const u64* __restrict__ keys,
                                                    const float* __restrict__ in,
                                                    float4* __restrict__ box4,
                                                    float4* __restrict__ boxoff4,
                                                    float* __restrict__ score,
                                                    float* __restrict__ cls,
                                                    u64* __restrict__ vmask,
                                                    float* __restrict__ out) {
    const int b = blockIdx.x, tid = threadIdx.x;
    const int lane = tid & 63, wv = tid >> 6;
    const u64* kb = keys + (size_t)b * NANCH;
    __shared__ u32 hist[4096];
    __shared__ u32 wtot[16];
    __shared__ u32 wsfx[16];
    __shared__ u32 s_prefix12, s_cnt;
    __shared__ u64 buf[2048];

    if (b == 0 && tid == 0) { out[0] = 0.0f; out[1] = 0.0f; }

#pragma unroll
    for (int i = 0; i < 4; ++i) hist[tid * 4 + i] = 0u;
    __syncthreads();
    // 12-bit histogram of the score's top bits.
#pragma unroll 4
    for (int n = tid; n < NANCH; n += 1024) {
        u32 hi = (u32)(kb[n] >> 32);
        atomicAdd(&hist[hi >> 20], 1u);
    }
    __syncthreads();
    // Hierarchical suffix scan: per-thread 4 bins -> wave shfl scan -> wave totals.
    u32 h0 = hist[tid * 4], h1 = hist[tid * 4 + 1];
    u32 h2 = hist[tid * 4 + 2], h3 = hist[tid * 4 + 3];
    u32 s3v = h3, s2v = h2 + s3v, s1v = h1 + s2v, s0v = h0 + s1v;
    u32 S = s0v;
#pragma unroll
    for (int d = 1; d < 64; d <<= 1) {
        u32 o = __shfl_down(S, d, 64);
        if (lane + d < 64) S += o;
    }
    if (lane == 0) wtot[wv] = S;          // sum of this wave's 256 bins
    __syncthreads();
    if (tid == 0) {
        u32 acc = 0;
        for (int w = 15; w >= 0; --w) { wsfx[w] = acc; acc += wtot[w]; }
    }
    __syncthreads();
    {
        const u32 E = wsfx[wv] + (S - s0v);   // suffix of bins strictly after ours
        const u32 v0 = E + s0v, v1 = E + s1v, v2 = E + s2v, v3 = E + s3v, v4 = E;
        if (v0 >= (u32)TOPK && v1 < (u32)TOPK) s_prefix12 = (u32)(tid * 4 + 0);
        if (v1 >= (u32)TOPK && v2 < (u32)TOPK) s_prefix12 = (u32)(tid * 4 + 1);
        if (v2 >= (u32)TOPK && v3 < (u32)TOPK) s_prefix12 = (u32)(tid * 4 + 2);
        if (v3 >= (u32)TOPK && v4 < (u32)TOPK) s_prefix12 = (u32)(tid * 4 + 3);
    }
    if (tid == 0) s_cnt = 0u;
    __syncthreads();
    const u32 p12 = s_prefix12;
    // Pass A: strictly greater 12-bit prefix (count < 1024 by construction).
#pragma unroll 4
    for (int n = tid; n < NANCH; n += 1024) {
        u64 k = kb[n];
        if (((u32)(k >> 32) >> 20) > p12) {
            u32 pos = atomicAdd(&s_cnt, 1u);
            if (pos < 2048u) buf[pos] = k;
        }
    }
    __syncthreads();
    // Pass B: equal 12-bit prefix (~1300 for this distribution; fits 2048).
#pragma unroll 4
    for (int n = tid; n < NANCH; n += 1024) {
        u64 k = kb[n];
        if (((u32)(k >> 32) >> 20) == p12) {
            u32 pos = atomicAdd(&s_cnt, 1u);
            if (pos < 2048u) buf[pos] = k;
        }
    }
    __syncthreads();
    u32 cnt = s_cnt; if (cnt > 2048u) cnt = 2048u;
    for (int n = (int)cnt + tid; n < 2048; n += 1024) buf[n] = 0ull;
    __syncthreads();

    // ---- hybrid bitonic sort, descending, 2048 u64 keys ----
    const int base = wv * 128;
    u64 r0 = buf[base + lane], r1 = buf[base + 64 + lane];
    for (int k2 = 2; k2 <= 128; k2 <<= 1) {
        const bool d0 = (((base + lane) & k2) == 0);
        const bool d1 = (((base + 64 + lane) & k2) == 0);
        for (int jj = (k2 >> 1); jj >= 1; jj >>= 1) {
            if (jj == 64) {
                u64 mx = r0 > r1 ? r0 : r1, mn = r0 > r1 ? r1 : r0;
                r0 = d0 ? mx : mn; r1 = d0 ? mn : mx;
            } else {
                const bool up = (lane & jj) != 0;
                u64 v0 = __shfl_xor(r0, jj, 64);
                u64 v1 = __shfl_xor(r1, jj, 64);
                const bool km0 = (d0 != up), km1 = (d1 != up);
                r0 = km0 ? (r0 > v0 ? r0 : v0) : (r0 < v0 ? r0 : v0);
                r1 = km1 ? (r1 > v1 ? r1 : v1) : (r1 < v1 ? r1 : v1);
            }
        }
    }
    for (int k2 = 256; k2 <= 2048; k2 <<= 1) {
        buf[base + lane] = r0; buf[base + 64 + lane] = r1;
        __syncthreads();
        for (int jj = (k2 >> 1); jj >= 128; jj >>= 1) {
            int i = ((tid & ~(jj - 1)) << 1) | (tid & (jj - 1));
            int part = i | jj;
            u64 a = buf[i], c = buf[part];
            bool sw = ((i & k2) == 0) ? (a < c) : (a > c);
            if (sw) { buf[i] = c; buf[part] = a; }
            __syncthreads();
        }
        r0 = buf[base + lane]; r1 = buf[base + 64 + lane];
        const bool d0 = (((base + lane) & k2) == 0);   // == d1 for k2 >= 256
        for (int jj = 64; jj >= 1; jj >>= 1) {
            if (jj == 64) {
                u64 mx = r0 > r1 ? r0 : r1, mn = r0 > r1 ? r1 : r0;
                r0 = d0 ? mx : mn; r1 = d0 ? mn : mx;
            } else {
                const bool up = (lane & jj) != 0;
                u64 v0 = __shfl_xor(r0, jj, 64);
                u64 v1 = __shfl_xor(r1, jj, 64);
                const bool km = (d0 != up);
                r0 = km ? (r0 > v0 ? r0 : v0) : (r0 < v0 ? r0 : v0);
                r1 = km ? (r1 > v1 ? r1 : v1) : (r1 < v1 ? r1 : v1);
            }
        }
    }
    buf[base + lane] = r0; buf[base + 64 + lane] = r1;
    __syncthreads();

    // Output rank tid (0..1023). cnt >= 1024 always, so buf[tid] is real.
    u64 k = buf[tid];
    u32 ord = (u32)(k >> 32);
    u32 sb = (ord & 0x80000000u) ? (ord ^ 0x80000000u) : ~ord;
    float sc = __uint_as_float(sb);
    int idx = (int)((((u32)(k >> 8)) & 0xFFFFu) ^ 0xFFFFu);
    int j = (int)(k & 0xFFu);
    const float* pr = in + ((size_t)b * NANCH + idx) * NFEAT;
    float cx = pr[0], cy = pr[1], ww = pr[2], hh = pr[3];
    float x1 = cx - ww / 2.0f, y1 = cy - hh / 2.0f;
    float x2 = cx + ww / 2.0f, y2 = cy + hh / 2.0f;
    float c = (float)j;
    float cm = c * MAX_WH;
    box4[b * TOPK + tid]    = make_float4(x1, y1, x2, y2);
    boxoff4[b * TOPK + tid] = make_float4(x1 + cm, y1 + cm, x2 + cm, y2 + cm);
    score[b * TOPK + tid] = sc;
    cls[b * TOPK + tid] = c;
    u64 bal = __ballot(sc > 0.0f);
    if ((tid & 63) == 0) vmask[b * 16 + (tid >> 6)] = bal;
}

// ---------------------------------------------------------------------------
// Kernel 3: suppression bitmask, row-major M[b][i][w] : bit l of
// M[(b*1024+i)*16+w] set iff iou(box_i, box_{64w+l}) > 0.45 && (64w+l) > i.
// Upper-triangle only: words w < i>>6 are structurally zero (j>i fails).
// NEW: stage only sbx[jmin..1023] (jmin = (i>>6)<<6, identical for the
// block's 4 rows) -- the lower-triangle columns are never read. Halves the
// 67 MB of L2 staging traffic on average.
// ---------------------------------------------------------------------------
__global__ __launch_bounds__(256) void iou_mask(const float4* __restrict__ boxoff4,
                                                u64* __restrict__ M) {
    __shared__ float4 sbx[TOPK];   // 16 KB (entries < jmin left unread)
    const int b = blockIdx.x >> 8;
    const int rb = blockIdx.x & 255;
    const int i = (rb << 2) | (threadIdx.x >> 6);
    const int lane = threadIdx.x & 63;
    const int tw = rb >> 4;          // == i >> 6 for all 4 rows of this block
    const int jmin = tw << 6;
    for (int t = jmin + threadIdx.x; t < TOPK; t += 256) sbx[t] = boxoff4[b * TOPK + t];
    __syncthreads();
    const float4 A = sbx[i];
    const float areaA = (A.z - A.x) * (A.w - A.y);
    u64 myword = 0ull;
#pragma unroll 4
    for (int t = tw; t < 16; ++t) {
        int j = (t << 6) | lane;
        float4 Bx = sbx[j];
        float lx = fmaxf(A.x, Bx.x), ly = fmaxf(A.y, Bx.y);
        float rx = fminf(A.z, Bx.z), ry = fminf(A.w, Bx.w);
        float iw = fmaxf(rx - lx, 0.0f), ih = fmaxf(ry - ly, 0.0f);
        float inter = iw * ih;
        float areaB = (Bx.z - Bx.x) * (Bx.w - Bx.y);
        float iou = inter / (areaA + areaB - inter + 1e-7f);
        bool pred = (iou > IOU_T) && (j > i);
        u64 bal = __ballot(pred);
        if (lane == t) myword = bal;
    }
    if (lane < 16) M[((size_t)b * TOPK + i) * 16 + lane] = myword;   // lanes < tw store 0
}

// ---------------------------------------------------------------------------
// Kernel 4: fused sequential NMS + finalize. One 512-thr block per batch.
// Phase 0: stage the batch's full 128 KB M into LDS (coalesced, 8 waves).
// Phase 1: lanes 0..15 of wave 0 run the greedy scan from LDS.
// NEW: per 16-row group, if no intra-group suppression edge exists
// (intra==0, the common case -- suppression matrix is sparse: ~13 boxes per
// class, few IoU>0.45 pairs), processing order within the group cannot
// change any group member's 'act', so the 16-step serial cndmask/or chain
// collapses to a depth-4 OR-tree over pre-masked rows (exact, ~6x shorter
// critical path). Fallback serial chain for intra!=0 groups.
// Phase 2: whole block builds det rows + fused reductions (atomics into out).
// ---------------------------------------------------------------------------
__global__ __launch_bounds__(512) void nms_finalize(const u64* __restrict__ M,
                                                    const u64* __restrict__ vmask,
                                                    const float4* __restrict__ box4,
                                                    const float* __restrict__ score,
                                                    const float* __restrict__ cls,
                                                    float* __restrict__ out) {
    __shared__ u64 sM[TOPK * 16];     // 131072 B (gfx950: 160 KB LDS)
    __shared__ u64 kw[16];
    __shared__ int wpfx[17];
    __shared__ float sdet[MAXDET * 6];
    __shared__ float s_sum, s_max;
    const int b = blockIdx.x, tid = threadIdx.x;
    // Stage M[b] -> LDS: 8192 ulonglong2, 16 coalesced rounds.
    {
        const ulonglong2* Ms = (const ulonglong2*)(M + (size_t)b * TOPK * 16);
        ulonglong2* Ldst = (ulonglong2*)sM;
#pragma unroll 4
        for (int t = tid; t < TOPK * 8; t += 512) Ldst[t] = Ms[t];
    }
    for (int t = tid; t < MAXDET * 6; t += 512) sdet[t] = 0.0f;
    if (tid == 0) { s_sum = 0.0f; s_max = 0.0f; }
    __syncthreads();
    if (tid < 16) {
        const int w = tid;
        const u64 vm = vmask[b * 16 + w];
        u64 supp = ~vm;
        u64 rwA[16], rwB[16];
#pragma unroll
        for (int q = 0; q < 16; ++q) rwA[q] = sM[q * 16 + w];   // rows 0..15
        for (int wb = 0; wb < 16; ++wb) {
            u64 cur = __shfl(supp, wb, 64);
#pragma unroll
            for (int c4 = 0; c4 < 4; ++c4) {
                const int rn = wb * 64 + (c4 + 1) * 16;   // prefetch next 16 rows
                if (rn < 1024) {
#pragma unroll
                    for (int q = 0; q < 16; ++q) rwB[q] = sM[(rn + q) * 16 + w];
                }
                u64 rc[16];
#pragma unroll
                for (int q = 0; q < 16; ++q) rc[q] = __shfl(rwA[q], wb, 64);
                // Any suppression edges INSIDE this 16-row window? (wave-uniform)
                u64 ar0 = rc[0] | rc[4] | rc[8]  | rc[12];
                u64 ar1 = rc[1] | rc[5] | rc[9]  | rc[13];
                u64 ar2 = rc[2] | rc[6] | rc[10] | rc[14];
                u64 ar3 = rc[3] | rc[7] | rc[11] | rc[15];
                const u32 intra = (u32)(((ar0 | ar1) | (ar2 | ar3)) >> (c4 * 16)) & 0xFFFFu;
                const u32 actm  = (~(u32)(cur >> (c4 * 16))) & 0xFFFFu;
                if (intra == 0u || actm == 0u) {
                    // Order-free: act of every group row is its initial cur bit.
                    u64 s0 = 0, s1 = 0, s2 = 0, s3 = 0;
                    u64 c0 = 0, c1 = 0, c2 = 0, c3 = 0;
#pragma unroll
                    for (int q = 0; q < 16; q += 4) {
                        const u64 m0 = ((actm >> (q + 0)) & 1u) ? ~0ull : 0ull;
                        const u64 m1 = ((actm >> (q + 1)) & 1u) ? ~0ull : 0ull;
                        const u64 m2 = ((actm >> (q + 2)) & 1u) ? ~0ull : 0ull;
                        const u64 m3 = ((actm >> (q + 3)) & 1u) ? ~0ull : 0ull;
                        s0 |= rwA[q + 0] & m0;  c0 |= rc[q + 0] & m0;
                        s1 |= rwA[q + 1] & m1;  c1 |= rc[q + 1] & m1;
                        s2 |= rwA[q + 2] & m2;  c2 |= rc[q + 2] & m2;
                        s3 |= rwA[q + 3] & m3;  c3 |= rc[q + 3] & m3;
                    }
                    supp |= (s0 | s1) | (s2 | s3);
                    cur  |= (c0 | c1) | (c2 | c3);
                } else {
                    // Exact serial fallback (rare: intra-group edges present).
#pragma unroll
                    for (int q = 0; q < 16; ++q) {
                        const int ii = c4 * 16 + q;            // compile-time 0..63
                        const bool act = ((cur >> ii) & 1ull) == 0ull;
                        supp = act ? (supp | rwA[q]) : supp;
                        cur  = act ? (cur  | rc[q])  : cur;
                    }
                }
#pragma unroll
                for (int q = 0; q < 16; ++q) rwA[q] = rwB[q];
            }
        }
        kw[w] = vm & ~supp;
    }
    __syncthreads();
    if (tid == 0) {
        int acc = 0;
        for (int w = 0; w < 16; ++w) { wpfx[w] = acc; acc += __popcll(kw[w]); }
        wpfx[16] = acc;
    }
    __syncthreads();
    for (int r = tid; r < TOPK; r += 512) {
        int w = r >> 6, bp = r & 63;
        if ((kw[w] >> bp) & 1ull) {
            int pos = wpfx[w] + __popcll(kw[w] & ((1ull << bp) - 1ull));
            if (pos < MAXDET) {
                float4 bx = box4[b * TOPK + r];
                float s = score[b * TOPK + r];
                float c = cls[b * TOPK + r];
                sdet[pos * 6 + 0] = bx.x;
                sdet[pos * 6 + 1] = bx.y;
                sdet[pos * 6 + 2] = bx.z;
                sdet[pos * 6 + 3] = bx.w;
                sdet[pos * 6 + 4] = s;
                sdet[pos * 6 + 5] = c;
                float term = (fabsf(bx.x - bx.z) + fabsf(bx.y - bx.w)) * s;
                atomicAdd(&s_sum, term);
                if (pos == 0) s_max = s;
            }
        }
    }
    __syncthreads();
    if (tid == 0) {
        int n = wpfx[16]; if (n > MAXDET) n = MAXDET;
        float wh = (n > 0) ? (s_sum / (2.0f * (float)n)) : 0.0f;
        atomicAdd(&out[0], s_max / (float)BATCH);
        atomicAdd(&out[1], wh / (float)BATCH);
    }
    if (b == 2) {
        for (int t = tid; t < MAXDET * 6; t += 512) out[2 + t] = sdet[t];
    }
}

extern "C" void kernel_launch(void* const* d_in, const int* in_sizes, int n_in,
                              void* d_out, int out_size, void* d_ws, size_t ws_size,
                              hipStream_t stream) {
    const float* in = (const float*)d_in[0];
    float* out = (float*)d_out;
    char* ws = (char*)d_ws;

    u64*    keys     = (u64*)   (ws + 0);                       // 3,225,600
    float4* boxoff4  = (float4*)(ws + 3225600);                 //   262,144
    float4* box4     = (float4*)(ws + 3487744);                 //   262,144
    float*  score    = (float*) (ws + 3749888);                 //    65,536
    float*  cls      = (float*) (ws + 3815424);                 //    65,536
    u64*    vmask    = (u64*)   (ws + 3880960);                 //     2,048
    u64*    M        = (u64*)   (ws + 3883008);                 // 2,097,152

    score_kernel<<<dim3(394, BATCH), 256, 0, stream>>>(in, keys);
    select_topk<<<BATCH, 1024, 0, stream>>>(keys, in, box4, boxoff4, score, cls, vmask, out);
    iou_mask<<<BATCH * 256, 256, 0, stream>>>(boxoff4, M);
    nms_finalize<<<BATCH, 512, 0, stream>>>(M, vmask, box4, score, cls, out);
}